// Round 7
// baseline (16985.591 us; speedup 1.0000x reference)
//
#include <hip/hip_runtime.h>
#include <hip/hip_bf16.h>

// Problem constants (B,T,D,L) = (16, 4096, 256, 512)
#define RNN_B 16
#define RNN_T 4096
#define RNN_D 256
#define RNN_L 512

typedef __fp16   fp16x2 __attribute__((ext_vector_type(2)));  // builtin-compatible
typedef _Float16 f16x8  __attribute__((ext_vector_type(8)));  // MFMA fragment
typedef float    f32x4  __attribute__((ext_vector_type(4)));

__device__ __forceinline__ unsigned pk2(float a, float b) {
    auto h = __builtin_amdgcn_cvt_pkrtz(a, b);   // __fp16 ext_vector(2)
    return __builtin_bit_cast(unsigned, h);
}

__device__ __forceinline__ float dot2u(unsigned wa, unsigned hb, float c) {
#if defined(__has_builtin) && __has_builtin(__builtin_amdgcn_fdot2)
    return __builtin_amdgcn_fdot2(__builtin_bit_cast(fp16x2, wa),
                                  __builtin_bit_cast(fp16x2, hb), c, false);
#else
    fp16x2 a = __builtin_bit_cast(fp16x2, wa), b = __builtin_bit_cast(fp16x2, hb);
    return c + (float)a[0] * (float)b[0] + (float)a[1] * (float)b[1];
#endif
}

// ---------------------------------------------------------------------------
// K1: Z[t,b,l] = sum_k x[b,t,k] * Wi[l,k] + bm[l], written as FLOAT32 into the
// hidden_states region of d_out (K2 reads it and overwrites with h in place).
// Tile 64(M) x 64(N), K-step 32, 4 waves, MFMA f32_16x16x32_f16.
// ---------------------------------------------------------------------------
__global__ __launch_bounds__(256) void proj_kernel(
        const float* __restrict__ x, const float* __restrict__ Wi,
        const float* __restrict__ bm, float* __restrict__ Zout) {
    __shared__ __align__(16) _Float16 As[64 * 40];  // +8 pad: 80B row stride
    __shared__ __align__(16) _Float16 Bs[64 * 40];

    const int bid = blockIdx.x;
    const int mt = bid >> 3, nt = bid & 7;
    const int mBase = mt * 64, nBase = nt * 64;
    const int tid = threadIdx.x;
    const int w = tid >> 6, l = tid & 63;

    // staging assignment: thread -> (row in tile, 8-wide k chunk)
    const int srow = tid >> 2, skc = (tid & 3) * 8;
    const int m = mBase + srow;
    const int bb = m & 15, tt = m >> 4;
    const float* ax = x + ((size_t)bb * RNN_T + tt) * RNN_D + skc;
    const float* bw = Wi + (size_t)(nBase + srow) * RNN_D + skc;

    f32x4 acc[4] = {};

#pragma unroll 1
    for (int k0 = 0; k0 < RNN_D; k0 += 32) {
        __syncthreads();
        float4 a0 = *(const float4*)(ax + k0);
        float4 a1 = *(const float4*)(ax + k0 + 4);
        float4 b0 = *(const float4*)(bw + k0);
        float4 b1 = *(const float4*)(bw + k0 + 4);
        uint4 ua = {pk2(a0.x, a0.y), pk2(a0.z, a0.w), pk2(a1.x, a1.y), pk2(a1.z, a1.w)};
        uint4 ub = {pk2(b0.x, b0.y), pk2(b0.z, b0.w), pk2(b1.x, b1.y), pk2(b1.z, b1.w)};
        *(uint4*)(As + srow * 40 + skc) = ua;
        *(uint4*)(Bs + srow * 40 + skc) = ub;
        __syncthreads();

        f16x8 af = *(const f16x8*)(As + (w * 16 + (l & 15)) * 40 + (l >> 4) * 8);
#pragma unroll
        for (int n = 0; n < 4; ++n) {
            f16x8 bf = *(const f16x8*)(Bs + (n * 16 + (l & 15)) * 40 + (l >> 4) * 8);
            acc[n] = __builtin_amdgcn_mfma_f32_16x16x32_f16(af, bf, acc[n], 0, 0, 0);
        }
    }

    // epilogue: C/D layout col = lane&15, row = (lane>>4)*4 + reg
    const int colL = l & 15, rg = l >> 4;
#pragma unroll
    for (int n = 0; n < 4; ++n) {
        const int col = nBase + n * 16 + colL;
        const float bias = bm[col];
#pragma unroll
        for (int q = 0; q < 4; ++q) {
            const int row = mBase + w * 16 + rg * 4 + q;
            Zout[(size_t)row * RNN_L + col] = acc[n][q] + bias;
        }
    }
}

// ---------------------------------------------------------------------------
// K2: sequential scan. 16 blocks (one per batch), 512 threads (8 waves).
// R4-R6 forensics: step time (3390 cyc) invariant under ALL register
// interventions -> bottleneck was the LDS pipe (512 broadcast ds_read_b128/step
// for h-ingestion ~2400 cyc). Fix: h is read from GLOBAL (L2-hot, all lanes
// same address -> one 16B transaction per load) on the idle VMEM pipe. The
// f16-packed h scratch lives in the out_o region (free until out_proj).
// LDS now holds only weights (144 KB, 18 uint4 groups); KRP=184 (210 live regs).
// __syncthreads drains vmcnt(0) before s_barrier -> stores visible to next
// step's loads. t=0 skips the matvec (h0 = 0), so scratch needs no init.
// ---------------------------------------------------------------------------
#define KRP 184                     // reg-resident f16x2 pairs per lane (k<368)
#define WG  18                      // uint4 weight groups per channel in LDS
#define K2_LDS_BYTES (WG * 512 * 16)   // 147456 = 144 KB

__global__ void
__attribute__((amdgpu_flat_work_group_size(512, 512)))
__attribute__((amdgpu_waves_per_eu(2, 2)))
rnn_scan(const float* __restrict__ Wm, float* __restrict__ out_h,
         unsigned* hscratch /* [16][256] u32, aliases out_o region */) {
    extern __shared__ __align__(16) char smem[];
    uint4* wlds = (uint4*)smem;                              // [WG][512] uint4

    const int b = blockIdx.x;
    const int tid = threadIdx.x, j = tid;

    // ---- prologue: load & pack Wm row j ----
    unsigned wreg[KRP];
    const float4* wrow = (const float4*)(Wm + (size_t)j * RNN_L);
#pragma unroll
    for (int f = 0; f < KRP / 2; ++f) {          // k in [0,368): 92 float4
        float4 v = wrow[f];
        wreg[2 * f]     = pk2(v.x, v.y);
        wreg[2 * f + 1] = pk2(v.z, v.w);
    }
    // Pin weights in VGPRs: opaque defs prevent the mid-end from sinking the
    // Wm loads into the t-loop. Zero instructions emitted.
#pragma unroll
    for (int g = 0; g < KRP; ++g) {
        asm volatile("" : "+v"(wreg[g]));
    }
#pragma unroll
    for (int gg = 0; gg < WG; ++gg) {            // k in [368,512) -> LDS
        float4 v0 = wrow[KRP / 2 + 2 * gg];
        float4 v1 = wrow[KRP / 2 + 2 * gg + 1];
        uint4 u = {pk2(v0.x, v0.y), pk2(v0.z, v0.w), pk2(v1.x, v1.y), pk2(v1.z, v1.w)};
        wlds[gg * 512 + j] = u;
    }
    __syncthreads();

    float* zh = out_h + (size_t)b * RNN_L + j;         // Z in, h out (f32)
    unsigned* hsc = hscratch + b * 256;                // f16x2-packed h
    const uint4* hws = (const uint4*)hsc;              // wave-uniform reads
    float z = zh[0];                                   // prefetched z for t=0

#pragma unroll 1
    for (int t = 0; t < RNN_T; ++t) {
        // prefetch z for t+1 (clamped; issues a full step before its use)
        const int tn = (t < RNN_T - 1) ? t + 1 : t;
        const float znext = zh[(size_t)tn * (RNN_B * RNN_L)];

        float acc = 0.f;
        if (t > 0) {
#pragma unroll
            for (int g = 0; g < KRP / 4; ++g) {  // k in [0,368): weights in VGPRs
                uint4 hh = hws[g];               // uniform addr -> 1 txn, L2-hot
                acc = dot2u(wreg[4 * g + 0], hh.x, acc);
                acc = dot2u(wreg[4 * g + 1], hh.y, acc);
                acc = dot2u(wreg[4 * g + 2], hh.z, acc);
                acc = dot2u(wreg[4 * g + 3], hh.w, acc);
            }
#pragma unroll
            for (int gg = 0; gg < WG; ++gg) {    // k in [368,512): weights in LDS
                uint4 ww = wlds[gg * 512 + j];   // 16B lane stride, conflict-free
                uint4 hh = hws[KRP / 4 + gg];
                acc = dot2u(ww.x, hh.x, acc);
                acc = dot2u(ww.y, hh.y, acc);
                acc = dot2u(ww.z, hh.z, acc);
                acc = dot2u(ww.w, hh.w, acc);
            }
        }

        const float pre = z + acc;
        const float hn = 1.f / (1.f + __expf(-pre));

        // stores: f32 h to output, f16x2-packed h pair to scratch (even lanes)
        zh[(size_t)t * (RNN_B * RNN_L)] = hn;
        const float hnb = __shfl_down(hn, 1);
        if (!(tid & 1)) hsc[j >> 1] = pk2(hn, hnb);

        __syncthreads();   // drains vmcnt(0): stores L2-visible to next step
        z = znext;
    }
}

// ---------------------------------------------------------------------------
// K3: o[t,b] = sum_j Wo[j] * h[t,b,j]. Memory-bound re-read of h (~134 MB).
// One wave per (t,b) row; 4 rows per 256-thread block. Overwrites the scratch
// region the scan used (deterministic final contents).
// ---------------------------------------------------------------------------
__global__ __launch_bounds__(256) void out_proj(
        const float* __restrict__ Wo, const float* __restrict__ h,
        float* __restrict__ o) {
    const int l = threadIdx.x & 63;
    const int r = blockIdx.x * 4 + (threadIdx.x >> 6);   // r = t*B + b
    const float4* hp = (const float4*)(h + (size_t)r * RNN_L);
    const float4* wp = (const float4*)Wo;
    float4 a0 = hp[l * 2], a1 = hp[l * 2 + 1];
    float4 b0 = wp[l * 2], b1 = wp[l * 2 + 1];
    float s = a0.x * b0.x + a0.y * b0.y + a0.z * b0.z + a0.w * b0.w
            + a1.x * b1.x + a1.y * b1.y + a1.z * b1.z + a1.w * b1.w;
#pragma unroll
    for (int off = 1; off < 64; off <<= 1) s += __shfl_xor(s, off);
    if (l == 0) o[r] = s;
}

// ---------------------------------------------------------------------------
extern "C" void kernel_launch(void* const* d_in, const int* in_sizes, int n_in,
                              void* d_out, int out_size, void* d_ws, size_t ws_size,
                              hipStream_t stream) {
    const float* x  = (const float*)d_in[0];   // [16,4096,256]
    const float* Wi = (const float*)d_in[1];   // [512,256]
    const float* Wm = (const float*)d_in[2];   // [512,512]
    const float* bm = (const float*)d_in[3];   // [512]
    const float* Wo = (const float*)d_in[4];   // [1,512]

    float* out_o = (float*)d_out;                 // [T*B] = 65536 floats
    float* out_h = out_o + (RNN_T * RNN_B);       // [T*B*L] floats

    // K1: Z = x @ Wi^T + bm  -> hidden_states region (scratch, overwritten by K2)
    proj_kernel<<<dim3((RNN_T * RNN_B / 64) * (RNN_L / 64)), dim3(256), 0, stream>>>(
        x, Wi, bm, out_h);

    // K2: sequential recurrence; h f16-scratch aliases out_o (free until K3)
    (void)hipFuncSetAttribute(reinterpret_cast<const void*>(rnn_scan),
                              hipFuncAttributeMaxDynamicSharedMemorySize, K2_LDS_BYTES);
    rnn_scan<<<dim3(RNN_B), dim3(512), K2_LDS_BYTES, stream>>>(
        Wm, out_h, (unsigned*)out_o);

    // K3: o = h . Wo (overwrites the scratch region with real outputs)
    out_proj<<<dim3(RNN_T * RNN_B / 4), dim3(256), 0, stream>>>(Wo, out_h, out_o);
}

// Round 8
// 5968.617 us; speedup vs baseline: 2.8458x; 2.8458x over previous
//
#include <hip/hip_runtime.h>
#include <hip/hip_bf16.h>

// Problem constants (B,T,D,L) = (16, 4096, 256, 512)
#define RNN_B 16
#define RNN_T 4096
#define RNN_D 256
#define RNN_L 512

typedef __fp16   fp16x2 __attribute__((ext_vector_type(2)));  // builtin-compatible
typedef _Float16 f16x8  __attribute__((ext_vector_type(8)));  // MFMA fragment
typedef float    f32x4  __attribute__((ext_vector_type(4)));

__device__ __forceinline__ unsigned pk2(float a, float b) {
    auto h = __builtin_amdgcn_cvt_pkrtz(a, b);   // __fp16 ext_vector(2)
    return __builtin_bit_cast(unsigned, h);
}

__device__ __forceinline__ uint4 pk4(float4 a, float4 b) {
    uint4 u;
    u.x = pk2(a.x, a.y); u.y = pk2(a.z, a.w);
    u.z = pk2(b.x, b.y); u.w = pk2(b.z, b.w);
    return u;
}

__device__ __forceinline__ float dot2u(unsigned wa, unsigned hb, float c) {
#if defined(__has_builtin) && __has_builtin(__builtin_amdgcn_fdot2)
    return __builtin_amdgcn_fdot2(__builtin_bit_cast(fp16x2, wa),
                                  __builtin_bit_cast(fp16x2, hb), c, false);
#else
    fp16x2 a = __builtin_bit_cast(fp16x2, wa), b = __builtin_bit_cast(fp16x2, hb);
    return c + (float)a[0] * (float)b[0] + (float)a[1] * (float)b[1];
#endif
}

// ---------------------------------------------------------------------------
// K1: Z[t,b,l] = sum_k x[b,t,k] * Wi[l,k] + bm[l] (f32 into hidden region).
// ---------------------------------------------------------------------------
__global__ __launch_bounds__(256) void proj_kernel(
        const float* __restrict__ x, const float* __restrict__ Wi,
        const float* __restrict__ bm, float* __restrict__ Zout) {
    __shared__ __align__(16) _Float16 As[64 * 40];
    __shared__ __align__(16) _Float16 Bs[64 * 40];

    const int bid = blockIdx.x;
    const int mt = bid >> 3, nt = bid & 7;
    const int mBase = mt * 64, nBase = nt * 64;
    const int tid = threadIdx.x;
    const int w = tid >> 6, l = tid & 63;

    const int srow = tid >> 2, skc = (tid & 3) * 8;
    const int m = mBase + srow;
    const int bb = m & 15, tt = m >> 4;
    const float* ax = x + ((size_t)bb * RNN_T + tt) * RNN_D + skc;
    const float* bw = Wi + (size_t)(nBase + srow) * RNN_D + skc;

    f32x4 acc[4] = {};

#pragma unroll 1
    for (int k0 = 0; k0 < RNN_D; k0 += 32) {
        __syncthreads();
        float4 a0 = *(const float4*)(ax + k0);
        float4 a1 = *(const float4*)(ax + k0 + 4);
        float4 b0 = *(const float4*)(bw + k0);
        float4 b1 = *(const float4*)(bw + k0 + 4);
        uint4 ua = {pk2(a0.x, a0.y), pk2(a0.z, a0.w), pk2(a1.x, a1.y), pk2(a1.z, a1.w)};
        uint4 ub = {pk2(b0.x, b0.y), pk2(b0.z, b0.w), pk2(b1.x, b1.y), pk2(b1.z, b1.w)};
        *(uint4*)(As + srow * 40 + skc) = ua;
        *(uint4*)(Bs + srow * 40 + skc) = ub;
        __syncthreads();

        f16x8 af = *(const f16x8*)(As + (w * 16 + (l & 15)) * 40 + (l >> 4) * 8);
#pragma unroll
        for (int n = 0; n < 4; ++n) {
            f16x8 bf = *(const f16x8*)(Bs + (n * 16 + (l & 15)) * 40 + (l >> 4) * 8);
            acc[n] = __builtin_amdgcn_mfma_f32_16x16x32_f16(af, bf, acc[n], 0, 0, 0);
        }
    }

    const int colL = l & 15, rg = l >> 4;
#pragma unroll
    for (int n = 0; n < 4; ++n) {
        const int col = nBase + n * 16 + colL;
        const float bias = bm[col];
#pragma unroll
        for (int q = 0; q < 4; ++q) {
            const int row = mBase + w * 16 + rg * 4 + q;
            Zout[(size_t)row * RNN_L + col] = acc[n][q] + bias;
        }
    }
}

// ---------------------------------------------------------------------------
// K2: sequential scan, k-split layout. 16 blocks (1/batch), 512 thr (8 waves).
// R4-R7 forensics: local ARRAYS of weights never promote to VGPRs (scratch,
// L2-resident, invisible in FETCH) and h-broadcasts saturated the LDS pipe
// (3390 cyc envelope, invariant to all register interventions).
// This version:
//  * 48 NAMED uint4 per lane (no arrays -> SSA -> real VGPRs), pinned.
//  * k-split: wave w owns k in [64w,64w+64); lane computes partials for its
//    8 channels (j = 8*(tid&63)+c) -> h-broadcast reads drop 512->64 per step.
//  * channels 0-5 weights in VGPR, channels 6-7 in LDS (128 KB, b128 clean).
//  * cross-wave reduce via padded part[8][8][65] f32 (2-way max = free).
//  * 2 barriers/step; h double-buffered as f16x2 in LDS; z prefetched.
// ---------------------------------------------------------------------------
#define WLDS_BYTES  131072                 // 16 groups x 512 threads x 16 B
#define PART_OFF    WLDS_BYTES             // 8*8*65 f32 = 16640 B
#define HBUF_OFF    (PART_OFF + 16640)     // 2*256 u32  = 2048 B
#define K2_LDS_BYTES (HBUF_OFF + 2048)     // 149760 <= 160 KB

#define DECL8(c) uint4 W##c##_0, W##c##_1, W##c##_2, W##c##_3, \
                       W##c##_4, W##c##_5, W##c##_6, W##c##_7
#define LOAD8(c) do { \
    const float4* p_ = (const float4*)(Wm + (size_t)(8 * l + (c)) * RNN_L + 64 * w); \
    W##c##_0 = pk4(p_[0], p_[1]);   W##c##_1 = pk4(p_[2], p_[3]); \
    W##c##_2 = pk4(p_[4], p_[5]);   W##c##_3 = pk4(p_[6], p_[7]); \
    W##c##_4 = pk4(p_[8], p_[9]);   W##c##_5 = pk4(p_[10], p_[11]); \
    W##c##_6 = pk4(p_[12], p_[13]); W##c##_7 = pk4(p_[14], p_[15]); } while (0)
#define PINU4(A, B) asm volatile("" : "+v"((A).x), "+v"((A).y), "+v"((A).z), "+v"((A).w), \
                                       "+v"((B).x), "+v"((B).y), "+v"((B).z), "+v"((B).w))
#define PIN8(c) do { PINU4(W##c##_0, W##c##_1); PINU4(W##c##_2, W##c##_3); \
                     PINU4(W##c##_4, W##c##_5); PINU4(W##c##_6, W##c##_7); } while (0)
#define DOT_U4(W, H, A) do { A = dot2u((W).x, (H).x, A); A = dot2u((W).y, (H).y, A); \
                             A = dot2u((W).z, (H).z, A); A = dot2u((W).w, (H).w, A); } while (0)
#define DOTH1(c) do { DOT_U4(W##c##_0, hh0, acc##c); DOT_U4(W##c##_1, hh1, acc##c); \
                      DOT_U4(W##c##_2, hh2, acc##c); DOT_U4(W##c##_3, hh3, acc##c); } while (0)
#define DOTH2(c) do { DOT_U4(W##c##_4, hh4, acc##c); DOT_U4(W##c##_5, hh5, acc##c); \
                      DOT_U4(W##c##_6, hh6, acc##c); DOT_U4(W##c##_7, hh7, acc##c); } while (0)
#define LDSDOT(g, H) do { uint4 ww6_ = wlds[(g) * 512 + tid]; DOT_U4(ww6_, H, acc6); \
                          uint4 ww7_ = wlds[((g) + 8) * 512 + tid]; DOT_U4(ww7_, H, acc7); } while (0)

__global__ void
__attribute__((amdgpu_flat_work_group_size(512, 512)))
__attribute__((amdgpu_waves_per_eu(2, 2)))
rnn_scan(const float* __restrict__ Wm, float* __restrict__ out_h) {
    extern __shared__ __align__(16) char smem[];
    uint4* wlds = (uint4*)smem;                       // [16][512] uint4
    float* part = (float*)(smem + PART_OFF);          // [8][8][65] f32
    unsigned* hbuf = (unsigned*)(smem + HBUF_OFF);    // [2][256] f16x2

    const int b = blockIdx.x;
    const int tid = threadIdx.x;
    const int w = tid >> 6, l = tid & 63;

    // ---- prologue: weights. ch 0-5 -> named VGPRs; ch 6,7 -> LDS ----
    DECL8(0); DECL8(1); DECL8(2); DECL8(3); DECL8(4); DECL8(5);
    LOAD8(0); LOAD8(1); LOAD8(2); LOAD8(3); LOAD8(4); LOAD8(5);
    PIN8(0); PIN8(1); PIN8(2); PIN8(3); PIN8(4); PIN8(5);
    {
        const float4* p6 = (const float4*)(Wm + (size_t)(8 * l + 6) * RNN_L + 64 * w);
        const float4* p7 = (const float4*)(Wm + (size_t)(8 * l + 7) * RNN_L + 64 * w);
#pragma unroll
        for (int g = 0; g < 8; ++g) {
            wlds[g * 512 + tid]       = pk4(p6[2 * g], p6[2 * g + 1]);
            wlds[(g + 8) * 512 + tid] = pk4(p7[2 * g], p7[2 * g + 1]);
        }
    }
    hbuf[tid] = 0;          // 512 u32 = both h buffers (h0 = 0)
    __syncthreads();

    float* zh = out_h + (size_t)b * RNN_L + tid;      // Z in, h out (f32)
    float z = zh[0];

#pragma unroll 1
    for (int t = 0; t < RNN_T; ++t) {
        const int cur = t & 1, nxt = cur ^ 1;
        const int tn = (t < RNN_T - 1) ? t + 1 : t;
        const float znext = zh[(size_t)tn * (RNN_B * RNN_L)];   // VMEM, hidden

        // ---- phase 1: partials over this wave's k-slice ----
        const uint4* hb4 = (const uint4*)(hbuf + cur * 256) + w * 8;  // uniform
        float acc0 = 0.f, acc1 = 0.f, acc2 = 0.f, acc3 = 0.f;
        float acc4 = 0.f, acc5 = 0.f, acc6 = 0.f, acc7 = 0.f;
        {
            uint4 hh0 = hb4[0], hh1 = hb4[1], hh2 = hb4[2], hh3 = hb4[3];
            DOTH1(0); DOTH1(1); DOTH1(2); DOTH1(3); DOTH1(4); DOTH1(5);
            LDSDOT(0, hh0); LDSDOT(1, hh1); LDSDOT(2, hh2); LDSDOT(3, hh3);
        }
        {
            uint4 hh4 = hb4[4], hh5 = hb4[5], hh6 = hb4[6], hh7 = hb4[7];
            DOTH2(0); DOTH2(1); DOTH2(2); DOTH2(3); DOTH2(4); DOTH2(5);
            LDSDOT(4, hh4); LDSDOT(5, hh5); LDSDOT(6, hh6); LDSDOT(7, hh7);
        }
        // part[c][w][l], inner dim padded to 65 (write: lanes consecutive)
        part[(0 * 8 + w) * 65 + l] = acc0;
        part[(1 * 8 + w) * 65 + l] = acc1;
        part[(2 * 8 + w) * 65 + l] = acc2;
        part[(3 * 8 + w) * 65 + l] = acc3;
        part[(4 * 8 + w) * 65 + l] = acc4;
        part[(5 * 8 + w) * 65 + l] = acc5;
        part[(6 * 8 + w) * 65 + l] = acc6;
        part[(7 * 8 + w) * 65 + l] = acc7;

        __syncthreads();   // B1: partials visible

        // ---- phase 2: thread tid reduces channel j = tid ----
        const int c2 = tid & 7, l2 = tid >> 3;
        float s = 0.f;
#pragma unroll
        for (int w2 = 0; w2 < 8; ++w2) s += part[(c2 * 8 + w2) * 65 + l2];

        const float pre = z + s;
        const float hn = 1.f / (1.f + __expf(-pre));

        const float hnb = __shfl_down(hn, 1);
        if (!(tid & 1)) hbuf[nxt * 256 + (tid >> 1)] = pk2(hn, hnb);

        __syncthreads();   // B2: next h buffer ready; partials reusable

        zh[(size_t)t * (RNN_B * RNN_L)] = hn;   // after barrier: never waited on
        z = znext;
    }
}

// ---------------------------------------------------------------------------
// K3: o[t,b] = sum_j Wo[j] * h[t,b,j]. Memory-bound re-read of h (~134 MB).
// ---------------------------------------------------------------------------
__global__ __launch_bounds__(256) void out_proj(
        const float* __restrict__ Wo, const float* __restrict__ h,
        float* __restrict__ o) {
    const int l = threadIdx.x & 63;
    const int r = blockIdx.x * 4 + (threadIdx.x >> 6);   // r = t*B + b
    const float4* hp = (const float4*)(h + (size_t)r * RNN_L);
    const float4* wp = (const float4*)Wo;
    float4 a0 = hp[l * 2], a1 = hp[l * 2 + 1];
    float4 b0 = wp[l * 2], b1 = wp[l * 2 + 1];
    float s = a0.x * b0.x + a0.y * b0.y + a0.z * b0.z + a0.w * b0.w
            + a1.x * b1.x + a1.y * b1.y + a1.z * b1.z + a1.w * b1.w;
#pragma unroll
    for (int off = 1; off < 64; off <<= 1) s += __shfl_xor(s, off);
    if (l == 0) o[r] = s;
}

// ---------------------------------------------------------------------------
extern "C" void kernel_launch(void* const* d_in, const int* in_sizes, int n_in,
                              void* d_out, int out_size, void* d_ws, size_t ws_size,
                              hipStream_t stream) {
    const float* x  = (const float*)d_in[0];   // [16,4096,256]
    const float* Wi = (const float*)d_in[1];   // [512,256]
    const float* Wm = (const float*)d_in[2];   // [512,512]
    const float* bm = (const float*)d_in[3];   // [512]
    const float* Wo = (const float*)d_in[4];   // [1,512]

    float* out_o = (float*)d_out;                 // [T*B] floats
    float* out_h = out_o + (RNN_T * RNN_B);       // [T*B*L] floats

    proj_kernel<<<dim3((RNN_T * RNN_B / 64) * (RNN_L / 64)), dim3(256), 0, stream>>>(
        x, Wi, bm, out_h);

    (void)hipFuncSetAttribute(reinterpret_cast<const void*>(rnn_scan),
                              hipFuncAttributeMaxDynamicSharedMemorySize, K2_LDS_BYTES);
    rnn_scan<<<dim3(RNN_B), dim3(512), K2_LDS_BYTES, stream>>>(Wm, out_h);

    out_proj<<<dim3(RNN_T * RNN_B / 4), dim3(256), 0, stream>>>(Wo, out_h, out_o);
}